// Round 3
// baseline (589.870 us; speedup 1.0000x reference)
//
#include <hip/hip_runtime.h>
#include <math.h>

// ---------------- problem constants ----------------
#define NB      32
#define NPTS    8192
#define TOTPTS  (NB * NPTS)        // 262144 points
#define TILE    512                // points per k_a block

typedef unsigned short u16;
typedef unsigned int   u32;
typedef __attribute__((ext_vector_type(8))) short bf16x8;  // 8 bf16 = 4 VGPR
typedef __attribute__((ext_vector_type(4))) float f32x4;   // MFMA C/D

__device__ __forceinline__ u16 f2bf(float f) {
    u32 u = __float_as_uint(f);
    u = (u + 0x7fffu + ((u >> 16) & 1u)) >> 16;   // RNE
    return (u16)u;
}
__device__ __forceinline__ u32 pk2(float a, float b) {
    return (u32)f2bf(a) | ((u32)f2bf(b) << 16);
}
__device__ __forceinline__ f32x4 MFMA(bf16x8 a, bf16x8 b, f32x4 c) {
    return __builtin_amdgcn_mfma_f32_16x16x32_bf16(a, b, c, 0, 0, 0);
}
// DPP max over the 16-lane row (point columns): xor1, xor2, then
// half_mirror (== xor4 on quad-reduced) and mirror (== xor8 on oct-reduced).
template<int CTRL>
__device__ __forceinline__ float dpp_max(float v) {
    int t = __builtin_amdgcn_update_dpp(__float_as_int(v), __float_as_int(v),
                                        CTRL, 0xF, 0xF, false);
    return fmaxf(v, __int_as_float(t));
}
__device__ __forceinline__ float rowmax16(float v) {
    v = dpp_max<0xB1>(v);    // quad_perm [1,0,3,2]  = xor1
    v = dpp_max<0x4E>(v);    // quad_perm [2,3,0,1]  = xor2
    v = dpp_max<0x141>(v);   // row_half_mirror      = xor4 (reduced)
    v = dpp_max<0x140>(v);   // row_mirror           = xor8 (reduced)
    return v;
}

// Fragment conventions (mfma_f32_16x16x32_bf16), verified round 2:
//   A: lane holds A[row=l&15][k=(l>>4)*8+j]  -> W[o][c] frag
//   B: lane holds B[k=(l>>4)*8+j][col=l&15]  -> H^T frag (col = point)
//   D: lane holds D[row=(l>>4)*4+r][col=l&15]
// Packed H: frag(pf,kf) at byte (pf*KF+kf)*1024 + lane*16.
// Packed W: frag(nf,kf) at byte (nf*KF+kf)*1024 + lane*16.

// ---------------- weight prepack (unchanged) ----------------
__global__ __launch_bounds__(256) void k_pack(const float* __restrict__ W2,
        const float* __restrict__ W3, const float* __restrict__ W4,
        const float* __restrict__ W5, u16* __restrict__ dst) {
    int idx = blockIdx.x * 256 + threadIdx.x;
    if (idx >= 720 * 64) return;
    int lane = idx & 63, fr = idx >> 6;
    const float* W; int C, frl;
    if (fr < 16)       { W = W2; C = 64;  frl = fr;       }
    else if (fr < 80)  { W = W3; C = 128; frl = fr - 16;  }
    else if (fr < 208) { W = W4; C = 256; frl = fr - 80;  }
    else               { W = W5; C = 256; frl = fr - 208; }
    int KF = C >> 5;
    int nf = frl / KF, kf = frl % KF;
    int o = nf * 16 + (lane & 15), c = kf * 32 + (lane >> 4) * 8;
    const float* s = W + (size_t)o * C + c;
    u32 out[4];
    #pragma unroll
    for (int j = 0; j < 4; ++j) out[j] = pk2(s[2 * j], s[2 * j + 1]);
    *(uint4*)((char*)dst + (size_t)idx * 16) = make_uint4(out[0], out[1], out[2], out[3]);
}

// ---------------- K_A: L1 (VALU 3->64) + L2 (MFMA 64->128), unchanged ----------------
__global__ __launch_bounds__(512) void k_a(const float* __restrict__ x,
        const float* __restrict__ W1, const float* __restrict__ b1,
        const u16* __restrict__ W2p, const float* __restrict__ b2,
        u16* __restrict__ H2p, int pt0) {
    __shared__ u16 H1[TILE * 64];
    const int tid = threadIdx.x, lane = tid & 63, w = tid >> 6;
    const int l15 = lane & 15, q = lane >> 4;
    const int t = blockIdx.x;
    const size_t ptbase = (size_t)pt0 + (size_t)t * TILE;
    const int b  = (int)(ptbase >> 13);
    const int nn = (int)(ptbase & 8191);

    const int myp = w * 64 + lane;
    const float* xb = x + (size_t)b * 3 * NPTS + nn + myp;
    const float x0 = xb[0], x1 = xb[NPTS], x2 = xb[2 * NPTS];
    {
        char* rowp = (char*)H1 + myp * 128;
        const int swz = (myp & 7) << 4;
        #pragma unroll
        for (int cb = 0; cb < 64; cb += 8) {
            u32 pkv[4];
            #pragma unroll
            for (int i = 0; i < 4; ++i) {
                int o0 = cb + 2 * i, o1 = o0 + 1;
                float a0 = fmaxf(b1[o0] + W1[o0*3]*x0 + W1[o0*3+1]*x1 + W1[o0*3+2]*x2, 0.f);
                float a1 = fmaxf(b1[o1] + W1[o1*3]*x0 + W1[o1*3+1]*x1 + W1[o1*3+2]*x2, 0.f);
                pkv[i] = pk2(a0, a1);
            }
            *(uint4*)(rowp + ((cb * 2) ^ swz)) = make_uint4(pkv[0], pkv[1], pkv[2], pkv[3]);
        }
    }
    __syncthreads();

    bf16x8 hb[2][4];
    #pragma unroll
    for (int kf = 0; kf < 2; ++kf)
        #pragma unroll
        for (int g = 0; g < 4; ++g) {
            int r2 = w * 64 + g * 16 + l15;
            hb[kf][g] = *(const bf16x8*)((const char*)H1 + r2 * 128 +
                                         ((kf * 64 + q * 16) ^ ((r2 & 7) << 4)));
        }
    const int qterm = ((q >> 1) * 16 + l15) * 16 + (q & 1) * 8;
    for (int nf = 0; nf < 8; ++nf) {
        f32x4 acc[4];
        f32x4 bv = *(const f32x4*)(b2 + nf * 16 + q * 4);
        #pragma unroll
        for (int g = 0; g < 4; ++g) acc[g] = bv;
        #pragma unroll
        for (int kf = 0; kf < 2; ++kf) {
            bf16x8 A = *(const bf16x8*)((const char*)W2p + (size_t)(nf * 2 + kf) * 1024 + lane * 16);
            #pragma unroll
            for (int g = 0; g < 4; ++g) acc[g] = MFMA(A, hb[kf][g], acc[g]);
        }
        #pragma unroll
        for (int g = 0; g < 4; ++g) {
            size_t pfc = (size_t)t * 32 + w * 4 + g;
            u32 d0 = pk2(fmaxf(acc[g][0], 0.f), fmaxf(acc[g][1], 0.f));
            u32 d1 = pk2(fmaxf(acc[g][2], 0.f), fmaxf(acc[g][3], 0.f));
            *(uint2*)((char*)H2p + (pfc * 4 + (nf >> 1)) * 1024 + (nf & 1) * 512 + qterm)
                = make_uint2(d0, d1);
        }
    }
}

// bid -> (zsl, pg) with pg-quad interleave: same-pg consumers stay within the
// residency window (and on <=2 XCDs) for L2/L3 reuse of the H input.
template<int ZSL>
__device__ __forceinline__ void decomp(int bid, int& zsl, int& pg) {
    int pgl = bid & 3;
    zsl = (bid >> 2) % ZSL;
    pg  = ((bid >> 2) / ZSL) * 4 + pgl;
}

// ---------------- K_MID: W-slice resident in LDS, barrier-free main loop ----
// Block: 4 waves, 32 point-frags, 8 nf (128 out-channels). ZSL=2 slices.
template<int KF>
__global__ __launch_bounds__(256) void k_mid(const u16* __restrict__ Hin,
        const u16* __restrict__ Wp, const float* __restrict__ bias,
        u16* __restrict__ Hout) {
    __shared__ u16 ldsW[8 * KF * 512];                 // 8 nf x KF frags
    constexpr int WBYTES = 8 * KF * 1024;              // 16/32 KB
    const int tid = threadIdx.x, lane = tid & 63, w = tid >> 6;
    const int l15 = lane & 15, q = lane >> 4;
    int zsl, pg; decomp<2>(blockIdx.x, zsl, pg);
    const int qterm = ((q >> 1) * 16 + l15) * 16 + (q & 1) * 8;

    const char* wsrc = (const char*)Wp + (size_t)zsl * WBYTES;
    #pragma unroll
    for (int i = 0; i < WBYTES / 4096; ++i)
        *(uint4*)((char*)ldsW + i * 4096 + tid * 16)
            = *(const uint4*)(wsrc + i * 4096 + tid * 16);
    __syncthreads();

    for (int gg = 0; gg < 2; ++gg) {
        bf16x8 hb[KF][4];
        #pragma unroll
        for (int kf = 0; kf < KF; ++kf)
            #pragma unroll
            for (int g = 0; g < 4; ++g) {
                size_t pf = (size_t)pg * 32 + w * 8 + gg * 4 + g;
                hb[kf][g] = *(const bf16x8*)((const char*)Hin + (pf * KF + kf) * 1024 + lane * 16);
            }
        for (int a = 0; a < 8; ++a) {
            const int nf = zsl * 8 + a;
            f32x4 acc[4];
            f32x4 bv = *(const f32x4*)(bias + nf * 16 + q * 4);
            #pragma unroll
            for (int g = 0; g < 4; ++g) acc[g] = bv;
            #pragma unroll
            for (int kf = 0; kf < KF; ++kf) {
                bf16x8 A = *(const bf16x8*)((const char*)ldsW + (size_t)(a * KF + kf) * 1024 + lane * 16);
                #pragma unroll
                for (int g = 0; g < 4; ++g) acc[g] = MFMA(A, hb[kf][g], acc[g]);
            }
            #pragma unroll
            for (int g = 0; g < 4; ++g) {              // KF_out = 8 (COUT 256)
                size_t pf = (size_t)pg * 32 + w * 8 + gg * 4 + g;
                u32 d0 = pk2(fmaxf(acc[g][0], 0.f), fmaxf(acc[g][1], 0.f));
                u32 d1 = pk2(fmaxf(acc[g][2], 0.f), fmaxf(acc[g][3], 0.f));
                *(uint2*)((char*)Hout + (pf * 8 + (nf >> 1)) * 1024 + (nf & 1) * 512 + qterm)
                    = make_uint2(d0, d1);
            }
        }
    }
}

// ---------------- K_L5: 256->1024 + max-pool, W-slice resident ----------------
// Block: 4 waves, 32 pf, 8 nf (128 z). ZSL=8. DPP point-reduce, no shfl/LDS.
__global__ __launch_bounds__(256) void k_l5(const u16* __restrict__ Hin,
        const u16* __restrict__ Wp, const float* __restrict__ b5,
        float* __restrict__ parts, int pg0) {
    __shared__ u16 ldsW[8 * 8 * 512];                  // 64 KB
    const int tid = threadIdx.x, lane = tid & 63, w = tid >> 6;
    const int l15 = lane & 15, q = lane >> 4;
    int zsl, pg; decomp<8>(blockIdx.x, zsl, pg);

    const char* wsrc = (const char*)Wp + (size_t)zsl * 65536;
    #pragma unroll
    for (int i = 0; i < 16; ++i)
        *(uint4*)((char*)ldsW + i * 4096 + tid * 16)
            = *(const uint4*)(wsrc + i * 4096 + tid * 16);
    __syncthreads();

    float out0 = -3.402823466e38f, out1 = -3.402823466e38f;

    for (int gg = 0; gg < 2; ++gg) {
        bf16x8 hb[8][4];
        #pragma unroll
        for (int kf = 0; kf < 8; ++kf)
            #pragma unroll
            for (int g = 0; g < 4; ++g) {
                size_t pf = (size_t)pg * 32 + w * 8 + gg * 4 + g;
                hb[kf][g] = *(const bf16x8*)((const char*)Hin + (pf * 8 + kf) * 1024 + lane * 16);
            }
        for (int a = 0; a < 8; ++a) {
            const int nf = zsl * 8 + a;
            f32x4 acc[4];
            f32x4 bv = *(const f32x4*)(b5 + nf * 16 + q * 4);
            #pragma unroll
            for (int g = 0; g < 4; ++g) acc[g] = bv;
            #pragma unroll
            for (int kf = 0; kf < 8; ++kf) {
                bf16x8 A = *(const bf16x8*)((const char*)ldsW + (size_t)(a * 8 + kf) * 1024 + lane * 16);
                #pragma unroll
                for (int g = 0; g < 4; ++g) acc[g] = MFMA(A, hb[kf][g], acc[g]);
            }
            // point-reduce: over g in-lane, then over the 16 cols via DPP.
            // keep-lane mapping: (a,r) -> l15 = a*2+(r>>1), slot = r&1.
            #pragma unroll
            for (int r = 0; r < 4; ++r) {
                float m = fmaxf(fmaxf(acc[0][r], acc[1][r]), fmaxf(acc[2][r], acc[3][r]));
                m = rowmax16(m);
                bool keep = (l15 == a * 2 + (r >> 1));
                if (r & 1) out1 = keep ? fmaxf(out1, m) : out1;
                else       out0 = keep ? fmaxf(out0, m) : out0;
            }
        }
    }
    // lane (q,l15) owns z = zsl*128 + (l15>>1)*16 + q*4 + (l15&1)*2 + slot
    float* dst = parts + ((size_t)(pg0 + pg) * 4 + w) * 1024
               + zsl * 128 + (l15 >> 1) * 16 + q * 4 + (l15 & 1) * 2;
    dst[0] = out0;
    dst[1] = out1;
}

// ---------------- final reduce: 512 pg x 4 waves -> [32][1024] ----------------
__global__ __launch_bounds__(256) void k_red(const float* __restrict__ parts,
                                             float* __restrict__ out) {
    int i = blockIdx.x * 256 + threadIdx.x;            // 32768
    int b = i >> 10, z = i & 1023;
    float m = -3.402823466e38f;
    for (int r = 0; r < 64; ++r)                       // 16 pg * 4 waves per batch
        m = fmaxf(m, parts[((size_t)b * 64 + r) * 1024 + z]);
    out[i] = m;
}

extern "C" void kernel_launch(void* const* d_in, const int* in_sizes, int n_in,
                              void* d_out, int out_size, void* d_ws, size_t ws_size,
                              hipStream_t stream) {
    const float* x  = (const float*)d_in[0];
    const float* W1 = (const float*)d_in[1]; const float* b1 = (const float*)d_in[2];
    const float* W2 = (const float*)d_in[3]; const float* b2 = (const float*)d_in[4];
    const float* W3 = (const float*)d_in[5]; const float* b3 = (const float*)d_in[6];
    const float* W4 = (const float*)d_in[7]; const float* b4 = (const float*)d_in[8];
    const float* W5 = (const float*)d_in[9]; const float* b5 = (const float*)d_in[10];

    u16* wsW = (u16*)d_ws;
    const u16* W2p = (const u16*)((char*)d_ws + 0);
    const u16* W3p = (const u16*)((char*)d_ws + 16 * 1024);
    const u16* W4p = (const u16*)((char*)d_ws + 80 * 1024);
    const u16* W5p = (const u16*)((char*)d_ws + 208 * 1024);
    float* parts   = (float*)((char*)d_ws + 786432);
    char* Hbase    = (char*)d_ws + 786432 + 16777216;

    int NCH = 2;
    while (NCH < 32) {
        size_t npc = (size_t)TOTPTS / NCH;
        if (786432 + 16777216 + npc * 1024 <= ws_size) break;
        NCH *= 2;
    }
    const size_t npts_c = (size_t)TOTPTS / NCH;
    char* HA = Hbase;
    char* HB = Hbase + npts_c * 512;

    k_pack<<<dim3(180), dim3(256), 0, stream>>>(W2, W3, W4, W5, wsW);

    const int ntc = (int)(npts_c / TILE);              // pg count per chunk
    for (int c = 0; c < NCH; ++c) {
        int pt0 = (int)(c * npts_c);
        int pg0 = pt0 / TILE;
        k_a<<<dim3(ntc), dim3(512), 0, stream>>>(x, W1, b1, W2p, b2, (u16*)HB, pt0);
        k_mid<4><<<dim3(2 * ntc), dim3(256), 0, stream>>>((const u16*)HB, W3p, b3, (u16*)HA);
        k_mid<8><<<dim3(2 * ntc), dim3(256), 0, stream>>>((const u16*)HA, W4p, b4, (u16*)HB);
        k_l5<<<dim3(8 * ntc), dim3(256), 0, stream>>>((const u16*)HB, W5p, b5, parts, pg0);
    }
    k_red<<<dim3(128), dim3(256), 0, stream>>>(parts, (float*)d_out);
}

// Round 4
// 210.580 us; speedup vs baseline: 2.8012x; 2.8012x over previous
//
#include <hip/hip_runtime.h>
#include <math.h>

// ---------------- problem constants ----------------
#define NB      32
#define NPTS    8192
#define TOTPTS  (NB * NPTS)        // 262144 points
#define TILE    512                // points per k_a block

typedef unsigned short u16;
typedef unsigned int   u32;
typedef __attribute__((ext_vector_type(8))) short bf16x8;  // 8 bf16 = 4 VGPR
typedef __attribute__((ext_vector_type(4))) float f32x4;   // MFMA C/D

__device__ __forceinline__ u16 f2bf(float f) {
    u32 u = __float_as_uint(f);
    u = (u + 0x7fffu + ((u >> 16) & 1u)) >> 16;   // RNE
    return (u16)u;
}
__device__ __forceinline__ u32 pk2(float a, float b) {
    return (u32)f2bf(a) | ((u32)f2bf(b) << 16);
}
__device__ __forceinline__ f32x4 MFMA(bf16x8 a, bf16x8 b, f32x4 c) {
    return __builtin_amdgcn_mfma_f32_16x16x32_bf16(a, b, c, 0, 0, 0);
}
template<int CTRL>
__device__ __forceinline__ float dpp_max(float v) {
    int t = __builtin_amdgcn_update_dpp(__float_as_int(v), __float_as_int(v),
                                        CTRL, 0xF, 0xF, false);
    return fmaxf(v, __int_as_float(t));
}
__device__ __forceinline__ float rowmax16(float v) {
    v = dpp_max<0xB1>(v);    // quad_perm xor1
    v = dpp_max<0x4E>(v);    // quad_perm xor2
    v = dpp_max<0x141>(v);   // row_half_mirror (xor4 on reduced)
    v = dpp_max<0x140>(v);   // row_mirror (xor8 on reduced)
    return v;
}
// async global->LDS, 16B per lane; LDS dest = wave-uniform base + lane*16
__device__ __forceinline__ void gload16(const void* g, void* l) {
    __builtin_amdgcn_global_load_lds(
        (const __attribute__((address_space(1))) unsigned int*)g,
        (__attribute__((address_space(3))) unsigned int*)l, 16, 0, 0);
}
template<int N> __device__ __forceinline__ void vwait() {
    if constexpr      (N == 0) asm volatile("s_waitcnt vmcnt(0)" ::: "memory");
    else if constexpr (N == 2) asm volatile("s_waitcnt vmcnt(2)" ::: "memory");
    else if constexpr (N == 4) asm volatile("s_waitcnt vmcnt(4)" ::: "memory");
    else                       asm volatile("s_waitcnt vmcnt(8)" ::: "memory");
}

// Fragment conventions (mfma_f32_16x16x32_bf16), verified rounds 2-3:
//   A: lane holds A[row=l&15][k=(l>>4)*8+j]  -> W[o][c] frag
//   B: lane holds B[k=(l>>4)*8+j][col=l&15]  -> H^T frag (col = point)
//   D: lane holds D[row=(l>>4)*4+r][col=l&15]
// Packed H: frag(pf,kf) at byte (pf*KF+kf)*1024 + lane*16.
// Packed W: frag(nf,kf) at byte (nf*KF+kf)*1024 + lane*16.

// ---------------- weight prepack (unchanged) ----------------
__global__ __launch_bounds__(256) void k_pack(const float* __restrict__ W2,
        const float* __restrict__ W3, const float* __restrict__ W4,
        const float* __restrict__ W5, u16* __restrict__ dst) {
    int idx = blockIdx.x * 256 + threadIdx.x;
    if (idx >= 720 * 64) return;
    int lane = idx & 63, fr = idx >> 6;
    const float* W; int C, frl;
    if (fr < 16)       { W = W2; C = 64;  frl = fr;       }
    else if (fr < 80)  { W = W3; C = 128; frl = fr - 16;  }
    else if (fr < 208) { W = W4; C = 256; frl = fr - 80;  }
    else               { W = W5; C = 256; frl = fr - 208; }
    int KF = C >> 5;
    int nf = frl / KF, kf = frl % KF;
    int o = nf * 16 + (lane & 15), c = kf * 32 + (lane >> 4) * 8;
    const float* s = W + (size_t)o * C + c;
    u32 out[4];
    #pragma unroll
    for (int j = 0; j < 4; ++j) out[j] = pk2(s[2 * j], s[2 * j + 1]);
    *(uint4*)((char*)dst + (size_t)idx * 16) = make_uint4(out[0], out[1], out[2], out[3]);
}

// ---------------- K_A: L1 (VALU 3->64) + L2 (MFMA 64->128), unchanged ----------------
__global__ __launch_bounds__(512) void k_a(const float* __restrict__ x,
        const float* __restrict__ W1, const float* __restrict__ b1,
        const u16* __restrict__ W2p, const float* __restrict__ b2,
        u16* __restrict__ H2p, int pt0) {
    __shared__ u16 H1[TILE * 64];
    const int tid = threadIdx.x, lane = tid & 63, w = tid >> 6;
    const int l15 = lane & 15, q = lane >> 4;
    const int t = blockIdx.x;
    const size_t ptbase = (size_t)pt0 + (size_t)t * TILE;
    const int b  = (int)(ptbase >> 13);
    const int nn = (int)(ptbase & 8191);

    const int myp = w * 64 + lane;
    const float* xb = x + (size_t)b * 3 * NPTS + nn + myp;
    const float x0 = xb[0], x1 = xb[NPTS], x2 = xb[2 * NPTS];
    {
        char* rowp = (char*)H1 + myp * 128;
        const int swz = (myp & 7) << 4;
        #pragma unroll
        for (int cb = 0; cb < 64; cb += 8) {
            u32 pkv[4];
            #pragma unroll
            for (int i = 0; i < 4; ++i) {
                int o0 = cb + 2 * i, o1 = o0 + 1;
                float a0 = fmaxf(b1[o0] + W1[o0*3]*x0 + W1[o0*3+1]*x1 + W1[o0*3+2]*x2, 0.f);
                float a1 = fmaxf(b1[o1] + W1[o1*3]*x0 + W1[o1*3+1]*x1 + W1[o1*3+2]*x2, 0.f);
                pkv[i] = pk2(a0, a1);
            }
            *(uint4*)(rowp + ((cb * 2) ^ swz)) = make_uint4(pkv[0], pkv[1], pkv[2], pkv[3]);
        }
    }
    __syncthreads();

    bf16x8 hb[2][4];
    #pragma unroll
    for (int kf = 0; kf < 2; ++kf)
        #pragma unroll
        for (int g = 0; g < 4; ++g) {
            int r2 = w * 64 + g * 16 + l15;
            hb[kf][g] = *(const bf16x8*)((const char*)H1 + r2 * 128 +
                                         ((kf * 64 + q * 16) ^ ((r2 & 7) << 4)));
        }
    const int qterm = ((q >> 1) * 16 + l15) * 16 + (q & 1) * 8;
    for (int nf = 0; nf < 8; ++nf) {
        f32x4 acc[4];
        f32x4 bv = *(const f32x4*)(b2 + nf * 16 + q * 4);
        #pragma unroll
        for (int g = 0; g < 4; ++g) acc[g] = bv;
        #pragma unroll
        for (int kf = 0; kf < 2; ++kf) {
            bf16x8 A = *(const bf16x8*)((const char*)W2p + (size_t)(nf * 2 + kf) * 1024 + lane * 16);
            #pragma unroll
            for (int g = 0; g < 4; ++g) acc[g] = MFMA(A, hb[kf][g], acc[g]);
        }
        #pragma unroll
        for (int g = 0; g < 4; ++g) {
            size_t pfc = (size_t)t * 32 + w * 4 + g;
            u32 d0 = pk2(fmaxf(acc[g][0], 0.f), fmaxf(acc[g][1], 0.f));
            u32 d1 = pk2(fmaxf(acc[g][2], 0.f), fmaxf(acc[g][3], 0.f));
            *(uint2*)((char*)H2p + (pfc * 4 + (nf >> 1)) * 1024 + (nf & 1) * 512 + qterm)
                = make_uint2(d0, d1);
        }
    }
}

// ---------------- K_MID v4: W in regs, B via async-LDS 3-buf pipeline ----------
// Block: 4 waves = 16 nf (all 256 out-ch); 16 pf per block, 2 pf per step.
template<int KF>
__global__ __launch_bounds__(256, 2) void k_mid(const u16* __restrict__ Hin,
        const u16* __restrict__ Wp, const float* __restrict__ bias,
        u16* __restrict__ Hout) {
    constexpr int BUFB = 2 * KF * 1024;           // step-tile bytes (8/16 KB)
    constexpr int NLD  = BUFB / 4096;             // global_load_lds per wave (2/4)
    constexpr int STEPS = 8;                      // 16 pf / 2
    __shared__ char ldsB[3 * BUFB];
    const int tid = threadIdx.x, lane = tid & 63, w = tid >> 6;
    const int l15 = lane & 15, q = lane >> 4;
    const int pfb = blockIdx.x * 16;
    const int qterm = ((q >> 1) * 16 + l15) * 16 + (q & 1) * 8;

    bf16x8 W[4][KF];                              // wave's 4 nf x KF (persistent)
    {
        const char* wb = (const char*)Wp + (size_t)(w * 4) * KF * 1024;
        #pragma unroll
        for (int nf = 0; nf < 4; ++nf)
            #pragma unroll
            for (int kf = 0; kf < KF; ++kf)
                W[nf][kf] = *(const bf16x8*)(wb + (size_t)(nf * KF + kf) * 1024 + lane * 16);
    }
    f32x4 bv[4];
    #pragma unroll
    for (int nf = 0; nf < 4; ++nf)
        bv[nf] = *(const f32x4*)(bias + (w * 4 + nf) * 16 + q * 4);

    auto stage = [&](int t, int bsel) {
        const char* g = (const char*)Hin + ((size_t)(pfb + t * 2) * KF) * 1024
                        + w * (NLD * 1024) + lane * 16;
        char* l = ldsB + bsel * BUFB + w * (NLD * 1024);
        #pragma unroll
        for (int i = 0; i < NLD; ++i)
            gload16(g + i * 1024, l + i * 1024);
    };
    stage(0, 0);
    stage(1, 1);
    int bufc = 0;
    for (int t = 0; t < STEPS; ++t) {
        if (t + 1 < STEPS) vwait<NLD>(); else vwait<0>();   // stage(t) landed
        __builtin_amdgcn_sched_barrier(0);
        __builtin_amdgcn_s_barrier();                       // all slices visible
        const char* bp = ldsB + bufc * BUFB;
        #pragma unroll
        for (int p = 0; p < 2; ++p) {
            f32x4 acc[4];
            #pragma unroll
            for (int nf = 0; nf < 4; ++nf) acc[nf] = bv[nf];
            #pragma unroll
            for (int kf = 0; kf < KF; ++kf) {
                bf16x8 B = *(const bf16x8*)(bp + (size_t)(p * KF + kf) * 1024 + lane * 16);
                #pragma unroll
                for (int nf = 0; nf < 4; ++nf) acc[nf] = MFMA(W[nf][kf], B, acc[nf]);
            }
            const size_t pf = (size_t)pfb + t * 2 + p;
            #pragma unroll
            for (int nf = 0; nf < 4; ++nf) {                // ReLU + store (KF_out=8)
                int nfg = w * 4 + nf;
                u32 d0 = pk2(fmaxf(acc[nf][0], 0.f), fmaxf(acc[nf][1], 0.f));
                u32 d1 = pk2(fmaxf(acc[nf][2], 0.f), fmaxf(acc[nf][3], 0.f));
                *(uint2*)((char*)Hout + (pf * 8 + (nfg >> 1)) * 1024 + (nfg & 1) * 512 + qterm)
                    = make_uint2(d0, d1);
            }
        }
        // issue stage(t+2) AFTER compute: barrier(t) guaranteed all waves left
        // compute(t-1), the last reader of buf[(t+2)%3]  -> no overwrite race.
        if (t + 2 < STEPS) {
            int b2 = bufc + 2; if (b2 >= 3) b2 -= 3;
            stage(t + 2, b2);
        }
        ++bufc; if (bufc == 3) bufc = 0;
    }
}

// ---------------- K_L5 v4: 256->1024 + max-pool; W regs, B async-LDS --------
// Block: 8 waves = 32 nf (zsl half of 1024 z); 64 pf per block, 2 pf/step.
__global__ __launch_bounds__(512, 2) void k_l5(const u16* __restrict__ Hin,
        const u16* __restrict__ Wp, const float* __restrict__ b5,
        float* __restrict__ parts, int slot0) {
    constexpr int BUFB = 16384;                   // 2 pf x 8 kf x 1KB
    constexpr int STEPS = 32;                     // 64 pf
    __shared__ char ldsB[3 * BUFB];               // 48 KB
    const int tid = threadIdx.x, lane = tid & 63, w = tid >> 6;
    const int l15 = lane & 15, q = lane >> 4;
    const int zsl = blockIdx.x & 1, pgrp = blockIdx.x >> 1;
    const int pfb = pgrp * 64;

    bf16x8 W[4][8];                               // 128 VGPR, persistent
    {
        const char* wb = (const char*)Wp + (size_t)(zsl * 32 + w * 4) * 8 * 1024;
        #pragma unroll
        for (int nf = 0; nf < 4; ++nf)
            #pragma unroll
            for (int kf = 0; kf < 8; ++kf)
                W[nf][kf] = *(const bf16x8*)(wb + (size_t)(nf * 8 + kf) * 1024 + lane * 16);
    }
    f32x4 vmax[4];
    #pragma unroll
    for (int nf = 0; nf < 4; ++nf)
        #pragma unroll
        for (int r = 0; r < 4; ++r) vmax[nf][r] = -3.402823466e38f;

    auto stage = [&](int t, int bsel) {
        const char* g = (const char*)Hin + ((size_t)(pfb + t * 2) * 8) * 1024
                        + w * 2048 + lane * 16;
        char* l = ldsB + bsel * BUFB + w * 2048;
        gload16(g, l);
        gload16(g + 1024, l + 1024);
    };
    stage(0, 0);
    stage(1, 1);
    int bufc = 0;
    for (int t = 0; t < STEPS; ++t) {
        if (t + 1 < STEPS) vwait<2>(); else vwait<0>();
        __builtin_amdgcn_sched_barrier(0);
        __builtin_amdgcn_s_barrier();
        const char* bp = ldsB + bufc * BUFB;
        #pragma unroll
        for (int p = 0; p < 2; ++p) {
            f32x4 acc[4];
            #pragma unroll
            for (int nf = 0; nf < 4; ++nf)
                #pragma unroll
                for (int r = 0; r < 4; ++r) acc[nf][r] = 0.f;
            #pragma unroll
            for (int kf = 0; kf < 8; ++kf) {
                bf16x8 B = *(const bf16x8*)(bp + (size_t)(p * 8 + kf) * 1024 + lane * 16);
                #pragma unroll
                for (int nf = 0; nf < 4; ++nf) acc[nf] = MFMA(W[nf][kf], B, acc[nf]);
            }
            #pragma unroll
            for (int nf = 0; nf < 4; ++nf)                 // deferred per-lane max
                #pragma unroll
                for (int r = 0; r < 4; ++r)
                    vmax[nf][r] = fmaxf(vmax[nf][r], acc[nf][r]);
        }
        if (t + 2 < STEPS) {
            int b2 = bufc + 2; if (b2 >= 3) b2 -= 3;
            stage(t + 2, b2);
        }
        ++bufc; if (bufc == 3) bufc = 0;
    }
    // one-time cross-lane reduce over the 16 point-columns, + bias, store
    const int zb = zsl * 512 + w * 64;
    float* dst = parts + (size_t)(slot0 + pgrp) * 1024 + zb;
    #pragma unroll
    for (int nf = 0; nf < 4; ++nf)
        #pragma unroll
        for (int r = 0; r < 4; ++r) {
            float m = rowmax16(vmax[nf][r]);
            if (l15 == nf * 4 + r) {
                int zi = nf * 16 + q * 4 + r;
                dst[zi] = m + b5[zb + zi];
            }
        }
}

// ---------------- final reduce: slot = 64-pf group; 8 slots per batch ---------
__global__ __launch_bounds__(256) void k_red(const float* __restrict__ parts,
                                             float* __restrict__ out) {
    int i = blockIdx.x * 256 + threadIdx.x;       // 32768
    int b = i >> 10, z = i & 1023;
    float m = -3.402823466e38f;
    #pragma unroll
    for (int s = 0; s < 8; ++s)
        m = fmaxf(m, parts[((size_t)b * 8 + s) * 1024 + z]);
    out[i] = m;
}

extern "C" void kernel_launch(void* const* d_in, const int* in_sizes, int n_in,
                              void* d_out, int out_size, void* d_ws, size_t ws_size,
                              hipStream_t stream) {
    const float* x  = (const float*)d_in[0];
    const float* W1 = (const float*)d_in[1]; const float* b1 = (const float*)d_in[2];
    const float* W2 = (const float*)d_in[3]; const float* b2 = (const float*)d_in[4];
    const float* W3 = (const float*)d_in[5]; const float* b3 = (const float*)d_in[6];
    const float* W4 = (const float*)d_in[7]; const float* b4 = (const float*)d_in[8];
    const float* W5 = (const float*)d_in[9]; const float* b5 = (const float*)d_in[10];

    u16* wsW = (u16*)d_ws;
    const u16* W2p = (const u16*)((char*)d_ws + 0);
    const u16* W3p = (const u16*)((char*)d_ws + 16 * 1024);
    const u16* W4p = (const u16*)((char*)d_ws + 80 * 1024);
    const u16* W5p = (const u16*)((char*)d_ws + 208 * 1024);
    float* parts   = (float*)((char*)d_ws + 786432);
    char* Hbase    = (char*)d_ws + 786432 + 16777216;

    int NCH = 2;
    while (NCH < 32) {
        size_t npc = (size_t)TOTPTS / NCH;
        if (786432 + 16777216 + npc * 1024 <= ws_size) break;
        NCH *= 2;
    }
    const size_t npts_c = (size_t)TOTPTS / NCH;
    char* HA = Hbase;
    char* HB = Hbase + npts_c * 512;

    k_pack<<<dim3(180), dim3(256), 0, stream>>>(W2, W3, W4, W5, wsW);

    const int ntc    = (int)(npts_c / TILE);       // k_a blocks per chunk
    const int npc_pf = (int)(npts_c / 16);         // point-frags per chunk
    for (int c = 0; c < NCH; ++c) {
        int pt0   = (int)(c * npts_c);
        int slot0 = (int)(((size_t)c * npc_pf) / 64);
        k_a<<<dim3(ntc), dim3(512), 0, stream>>>(x, W1, b1, W2p, b2, (u16*)HB, pt0);
        k_mid<4><<<dim3(npc_pf / 16), dim3(256), 0, stream>>>((const u16*)HB, W3p, b3, (u16*)HA);
        k_mid<8><<<dim3(npc_pf / 16), dim3(256), 0, stream>>>((const u16*)HA, W4p, b4, (u16*)HB);
        k_l5<<<dim3(2 * (npc_pf / 64)), dim3(512), 0, stream>>>((const u16*)HB, W5p, b5, parts, slot0);
    }
    k_red<<<dim3(128), dim3(256), 0, stream>>>(parts, (float*)d_out);
}